// Round 2
// baseline (296.994 us; speedup 1.0000x reference)
//
#include <hip/hip_runtime.h>
#include <hip/hip_bf16.h>

// NodeDetector: per-node-masked 2-layer GATv2 forward, delta formulation.
// N=256 nodes, C2=64, H=2 heads, E=4352 edges (incl. self loops).
// Only row i of `proj` changes per mask iteration i, so:
//   - layer-1 outputs change only for A_i = {i} ∪ out-neighbors(i)
//   - layer-2 is needed only at node i.
// Robustness this round: (a) input dtype auto-detected (bf16 vs f32) since the
// harness's conversion policy is ambiguous; (b) all scratch in __device__
// globals — d_ws is not used at all (ws_size unknown => overflow risk).

#define NN 256
#define EDGE_CAP 96   // max in-degree supported (actual max ~35)
#define E2_CAP 64     // max in-degree for layer-2 edge buffer
#define E_CAP 6144    // max edges (actual 4352)

// ---- persistent device-global scratch ----
__device__ float g_xl0[NN*128], g_xr0[NN*128], g_xlV[NN*128], g_xrV[NN*128];
__device__ float g_g1_0[NN*64], g_xl2_0[NN*128];
__device__ int   g_in_ptr[NN+1], g_out_ptr[NN+1];
__device__ int   g_in_src[E_CAP], g_out_dst[E_CAP];
__device__ int   g_f32;   // 1 => float32 inputs/output, 0 => bf16

typedef const void* cvp;
__device__ __forceinline__ float b2f(__hip_bfloat16 v) { return __bfloat162float(v); }
// uniform-predicate dual-dtype load (branch kept: loads are not speculable)
__device__ __forceinline__ float ldin(cvp p, int i, int f) {
  if (f) return ((const float*)p)[i];
  return b2f(((const __hip_bfloat16*)p)[i]);
}

// ---------------------------------------------------------------------------
// K0: dtype detection. Reading f32 data as bf16 makes ~half the even-index
// elements decode to |v|>16 or NaN (mantissa bits land in the exponent field);
// genuine bf16 N(0,1) data has none.
// ---------------------------------------------------------------------------
__global__ __launch_bounds__(256) void k_detect(cvp x, int n) {
  __shared__ int cnt;
  if (threadIdx.x == 0) cnt = 0;
  __syncthreads();
  const __hip_bfloat16* xb = (const __hip_bfloat16*)x;
  const int lim = n < 4096 ? n : 4096;
  int c = 0;
  for (int i = threadIdx.x; i < lim; i += 256) {
    const float v = b2f(xb[i]);
    if (!(fabsf(v) <= 16.f)) c++;   // counts NaN too
  }
  atomicAdd(&cnt, c);
  __syncthreads();
  if (threadIdx.x == 0) g_f32 = (cnt > 64) ? 1 : 0;
}

// ---------------------------------------------------------------------------
// K1: shared dense precompute. One block per node j (128 threads).
// Produces xl0/xr0 (baseline GATv2-1 transforms) and xlV/xrV (the values row i
// takes when it is the masked node).
// ---------------------------------------------------------------------------
__global__ __launch_bounds__(128) void k_dense(
    cvp x, cvp E_emb, cvp node_proj, cvp emb_proj,
    cvp conv_w0, cvp conv_w1, cvp conv_b,
    cvp lin2_w, cvp lin2_b, cvp masked_proj, cvp normal_proj,
    cvp g1_wl, cvp g1_bl, cvp g1_wr, cvp g1_br)
{
  const int j = blockIdx.x, t = threadIdx.x;
  const int f = g_f32;
  __shared__ float sx[64], sE[64], sxp[128], sEp[128], sh0[128], shm[128],
                   sm0[64], sMm[64], sp0[64], sV[64];
  if (t < 64) { sx[t] = ldin(x, j*64+t, f); sE[t] = ldin(E_emb, j*64+t, f); }
  __syncthreads();
  // x_p, E_p  [128]
  float a = 0.f, b = 0.f;
  for (int k = 0; k < 64; ++k) {
    a += sx[k] * ldin(node_proj, k*128+t, f);
    b += sE[k] * ldin(emb_proj,  k*128+t, f);
  }
  sxp[t] = a; sEp[t] = b;
  __syncthreads();
  // x_w1, E_p@conv_w0 ; h0 = tanh(base), hm = tanh(base - x_w1)
  float xw1 = 0.f, ew0 = 0.f;
  for (int k = 0; k < 128; ++k) {
    xw1 += sxp[k] * ldin(conv_w1, k*128+t, f);
    ew0 += sEp[k] * ldin(conv_w0, k*128+t, f);
  }
  const float cb = ldin(conv_b, t, f);
  sh0[t] = tanhf(ew0 + xw1 + cb);
  shm[t] = tanhf(ew0 + cb);
  __syncthreads();
  if (t < 64) {
    float m0 = ldin(lin2_b, t, f), Mm = m0;
    for (int k = 0; k < 128; ++k) {
      const float w = ldin(lin2_w, k*64+t, f);
      m0 += sh0[k]*w; Mm += shm[k]*w;
    }
    sm0[t] = m0; sMm[t] = Mm;
  }
  __syncthreads();
  if (t < 64) {
    float p = 0.f, v = 0.f;
    for (int k = 0; k < 64; ++k) {
      p += sm0[k] * ldin(normal_proj, k*64+t, f);
      v += sMm[k] * ldin(masked_proj, k*64+t, f);
    }
    sp0[t] = p; sV[t] = v;
  }
  __syncthreads();
  // GATv2-1 source/target transforms for baseline row and masked-row value
  float l0 = ldin(g1_bl, t, f), r0 = ldin(g1_br, t, f);
  float lV = l0, rV = r0;
  for (int k = 0; k < 64; ++k) {
    const float wl = ldin(g1_wl, k*128+t, f), wr = ldin(g1_wr, k*128+t, f);
    l0 += sp0[k]*wl; r0 += sp0[k]*wr;
    lV += sV[k]*wl;  rV += sV[k]*wr;
  }
  g_xl0[j*128+t] = l0; g_xr0[j*128+t] = r0;
  g_xlV[j*128+t] = lV; g_xrV[j*128+t] = rV;
}

// ---------------------------------------------------------------------------
// K2: CSR build (by dst for attention, by src for affected sets). 1 block.
// ---------------------------------------------------------------------------
__global__ __launch_bounds__(256) void k_csr(const int* __restrict__ ei, int E)
{
  __shared__ int cin[NN], cou[NN], pin[NN+1], pou[NN+1];
  const int t = threadIdx.x;
  if (E > E_CAP) E = E_CAP;
  cin[t] = 0; cou[t] = 0;
  __syncthreads();
  for (int e = t; e < E; e += 256) {
    atomicAdd(&cin[ei[E+e] & (NN-1)], 1);
    atomicAdd(&cou[ei[e]   & (NN-1)], 1);
  }
  __syncthreads();
  if (t == 0) {
    int si = 0, so = 0;
    for (int n = 0; n < NN; ++n) { pin[n] = si; si += cin[n]; pou[n] = so; so += cou[n]; }
    pin[NN] = si; pou[NN] = so;
  }
  __syncthreads();
  g_in_ptr[t] = pin[t]; g_out_ptr[t] = pou[t];
  if (t == 0) { g_in_ptr[NN] = pin[NN]; g_out_ptr[NN] = pou[NN]; }
  cin[t] = pin[t]; cou[t] = pou[t];
  __syncthreads();
  for (int e = t; e < E; e += 256) {
    const int s = ei[e] & (NN-1), d = ei[E+e] & (NN-1);
    g_in_src[atomicAdd(&cin[d], 1)] = s;
    g_out_dst[atomicAdd(&cou[s], 1)] = d;
  }
}

// ---------------------------------------------------------------------------
// K3: baseline layer-1 attention -> g1_0, and xl2_0 = elu-out @ g2_wl + g2_bl.
// One block per node j (128 threads = 2 waves, one per head for reductions).
// ---------------------------------------------------------------------------
__global__ __launch_bounds__(128) void k_l1base(
    cvp g1_att, cvp g1_bias, cvp g2_wl, cvp g2_bl)
{
  const int j = blockIdx.x, t = threadIdx.x;
  const int f = g_f32;
  __shared__ float sxr[128], satt[128], slog[2][EDGE_CAP], sw[2][EDGE_CAP];
  __shared__ float sinv[2], sagg[128], sg1[64];
  __shared__ int ssrc[EDGE_CAP];
  const int base = g_in_ptr[j];
  int nE = g_in_ptr[j+1] - base;
  if (nE > EDGE_CAP) nE = EDGE_CAP;
  sxr[t] = g_xr0[j*128+t];
  satt[t] = ldin(g1_att, t, f);
  for (int e = t; e < nE; e += 128) ssrc[e] = g_in_src[base+e];
  __syncthreads();
  for (int idx = t; idx < nE*2; idx += 128) {
    const int e = idx >> 1, h = idx & 1, s = ssrc[e];
    const float* xls = g_xl0 + s*128 + h*64;
    float acc = 0.f;
    for (int c = 0; c < 64; ++c) {
      float v = xls[c] + sxr[h*64+c];
      v = v > 0.f ? v : 0.2f*v;
      acc += satt[h*64+c]*v;
    }
    slog[h][e] = acc;
  }
  __syncthreads();
  {
    const int h = t >> 6, lane = t & 63;
    float m = -1e30f;
    for (int e = lane; e < nE; e += 64) m = fmaxf(m, slog[h][e]);
    for (int o = 1; o < 64; o <<= 1) m = fmaxf(m, __shfl_xor(m, o));
    float ssum = 0.f;
    for (int e = lane; e < nE; e += 64) { const float w = __expf(slog[h][e]-m); sw[h][e] = w; ssum += w; }
    for (int o = 1; o < 64; o <<= 1) ssum += __shfl_xor(ssum, o);
    if (lane == 0) sinv[h] = 1.f/(ssum + 1e-16f);
  }
  __syncthreads();
  {
    const int h = t >> 6, c = t & 63;
    float acc = 0.f;
    for (int e = 0; e < nE; ++e) acc += sw[h][e]*g_xl0[ssrc[e]*128 + h*64 + c];
    sagg[t] = acc*sinv[h];
  }
  __syncthreads();
  if (t < 64) {
    float g = 0.5f*(sagg[t]+sagg[64+t]) + ldin(g1_bias, t, f);
    g = g > 0.f ? g : expm1f(g);
    sg1[t] = g; g_g1_0[j*64+t] = g;
  }
  __syncthreads();
  float acc = ldin(g2_bl, t, f);
  for (int k = 0; k < 64; ++k) acc += sg1[k]*ldin(g2_wl, k*128+t, f);
  g_xl2_0[j*128+t] = acc;
}

// ---------------------------------------------------------------------------
// K4: per-mask-iteration kernel. Block i handles mask position i:
//   1. A_i = unique dsts of out-edges of i (self loop => i in A_i)
//   2. recompute layer-1 at each j in A_i with row i's xl/xr replaced by V-vals
//   3. layer-2 attention at node i only; reconstruction head; tanh; output
// ---------------------------------------------------------------------------
__global__ __launch_bounds__(256) void k_periter(
    cvp g1_att, cvp g1_bias, cvp g2_wl, cvp g2_bl, cvp g2_wr, cvp g2_br,
    cvp g2_att, cvp g2_bias, cvp rec_w, cvp rec_b, void* out)
{
  const int i = blockIdx.x, t = threadIdx.x;
  const int f = g_f32;
  __shared__ int slotOf[NN];      // node -> slot in g1n, or -1
  __shared__ int listA[64];
  __shared__ int nA;
  __shared__ float g1n[64*64];    // recomputed layer-1 outputs (changed nodes)
  __shared__ float xl2e[E2_CAP*128];
  __shared__ float satt[128], satt2[128];
  __shared__ int ssrc[EDGE_CAP];
  __shared__ float slog[2][EDGE_CAP], sw[2][EDGE_CAP], sinv[2], sagg[128];
  __shared__ float sxr[128], xr2i[128], sg[64];

  if (t < NN) slotOf[t] = -1;
  if (t == 0) nA = 0;
  if (t < 128) { satt[t] = ldin(g1_att, t, f); satt2[t] = ldin(g2_att, t, f); }
  __syncthreads();

  // ---- affected set ----
  const int ob = g_out_ptr[i], onE = g_out_ptr[i+1] - ob;
  for (int e = t; e < onE; e += 256) {
    const int d = g_out_dst[ob+e];
    if (atomicCAS(&slotOf[d], -1, -2) == -1) {
      const int p = atomicAdd(&nA, 1);
      if (p < 64) { listA[p] = d; slotOf[d] = p; }
      else slotOf[d] = -1;  // overflow (never happens for this graph)
    }
  }
  __syncthreads();
  int nAl = nA; if (nAl > 64) nAl = 64;

  // ---- recompute layer-1 at each affected node ----
  for (int a = 0; a < nAl; ++a) {
    const int j = listA[a];
    const int base = g_in_ptr[j];
    int nE = g_in_ptr[j+1] - base;
    if (nE > EDGE_CAP) nE = EDGE_CAP;
    if (t < 128) sxr[t] = (j == i) ? g_xrV[i*128+t] : g_xr0[j*128+t];
    for (int e = t; e < nE; e += 256) ssrc[e] = g_in_src[base+e];
    __syncthreads();
    for (int idx = t; idx < nE*2; idx += 256) {
      const int e = idx >> 1, h = idx & 1, s = ssrc[e];
      const float* xls = ((s == i) ? g_xlV : g_xl0) + s*128 + h*64;
      float acc = 0.f;
      for (int c = 0; c < 64; ++c) {
        float v = xls[c] + sxr[h*64+c];
        v = v > 0.f ? v : 0.2f*v;
        acc += satt[h*64+c]*v;
      }
      slog[h][e] = acc;
    }
    __syncthreads();
    if (t < 128) {
      const int h = t >> 6, lane = t & 63;
      float m = -1e30f;
      for (int e = lane; e < nE; e += 64) m = fmaxf(m, slog[h][e]);
      for (int o = 1; o < 64; o <<= 1) m = fmaxf(m, __shfl_xor(m, o));
      float ssum = 0.f;
      for (int e = lane; e < nE; e += 64) { const float w = __expf(slog[h][e]-m); sw[h][e] = w; ssum += w; }
      for (int o = 1; o < 64; o <<= 1) ssum += __shfl_xor(ssum, o);
      if (lane == 0) sinv[h] = 1.f/(ssum + 1e-16f);
    }
    __syncthreads();
    if (t < 128) {
      const int h = t >> 6, c = t & 63;
      float acc = 0.f;
      for (int e = 0; e < nE; ++e) {
        const int s = ssrc[e];
        const float* xls = ((s == i) ? g_xlV : g_xl0) + s*128;
        acc += sw[h][e]*xls[h*64+c];
      }
      sagg[t] = acc*sinv[h];
    }
    __syncthreads();
    if (t < 64) {
      float g = 0.5f*(sagg[t]+sagg[64+t]) + ldin(g1_bias, t, f);
      g = g > 0.f ? g : expm1f(g);
      g1n[a*64+t] = g;
    }
    __syncthreads();
  }

  // ---- layer 2 at node i ----
  const int b2 = g_in_ptr[i];
  int nE2 = g_in_ptr[i+1] - b2;
  if (nE2 > E2_CAP) nE2 = E2_CAP;
  for (int e = t; e < nE2; e += 256) ssrc[e] = g_in_src[b2+e];
  __syncthreads();
  // per-edge xl2: changed sources recomputed, others from precompute
  for (int idx = t; idx < nE2*128; idx += 256) {
    const int e = idx >> 7, c = idx & 127, s = ssrc[e];
    const int sl = slotOf[s];
    float v;
    if (sl >= 0) {
      v = ldin(g2_bl, c, f);
      const float* g1r = g1n + sl*64;
      for (int k = 0; k < 64; ++k) v += g1r[k]*ldin(g2_wl, k*128+c, f);
    } else {
      v = g_xl2_0[s*128+c];
    }
    xl2e[e*128+c] = v;
  }
  if (t < 128) {
    int sli = slotOf[i]; if (sli < 0) sli = 0;  // i always in A_i (self loop)
    float v = ldin(g2_br, t, f);
    const float* g1r = g1n + sli*64;
    for (int k = 0; k < 64; ++k) v += g1r[k]*ldin(g2_wr, k*128+t, f);
    xr2i[t] = v;
  }
  __syncthreads();
  for (int idx = t; idx < nE2*2; idx += 256) {
    const int e = idx >> 1, h = idx & 1;
    const float* xle = xl2e + e*128 + h*64;
    float acc = 0.f;
    for (int c = 0; c < 64; ++c) {
      float v = xle[c] + xr2i[h*64+c];
      v = v > 0.f ? v : 0.2f*v;
      acc += satt2[h*64+c]*v;
    }
    slog[h][e] = acc;
  }
  __syncthreads();
  if (t < 128) {
    const int h = t >> 6, lane = t & 63;
    float m = -1e30f;
    for (int e = lane; e < nE2; e += 64) m = fmaxf(m, slog[h][e]);
    for (int o = 1; o < 64; o <<= 1) m = fmaxf(m, __shfl_xor(m, o));
    float ssum = 0.f;
    for (int e = lane; e < nE2; e += 64) { const float w = __expf(slog[h][e]-m); sw[h][e] = w; ssum += w; }
    for (int o = 1; o < 64; o <<= 1) ssum += __shfl_xor(ssum, o);
    if (lane == 0) sinv[h] = 1.f/(ssum + 1e-16f);
  }
  __syncthreads();
  if (t < 128) {
    const int h = t >> 6, c = t & 63;
    float acc = 0.f;
    for (int e = 0; e < nE2; ++e) acc += sw[h][e]*xl2e[e*128 + h*64 + c];
    sagg[t] = acc*sinv[h];
  }
  __syncthreads();
  if (t < 64) {
    float g = 0.5f*(sagg[t]+sagg[64+t]) + ldin(g2_bias, t, f);
    g = g > 0.f ? g : expm1f(g);
    sg[t] = g;
  }
  __syncthreads();
  if (t < 64) {
    float v = ldin(rec_b, t, f);
    for (int c = 0; c < 64; ++c) v += sg[c]*ldin(rec_w, c*64+t, f);
    const float r = tanhf(v);
    if (f) ((float*)out)[i*64+t] = r;
    else   ((__hip_bfloat16*)out)[i*64+t] = __float2bfloat16(r);
  }
}

// ---------------------------------------------------------------------------
extern "C" void kernel_launch(void* const* d_in, const int* in_sizes, int n_in,
                              void* d_out, int out_size, void* d_ws, size_t ws_size,
                              hipStream_t stream)
{
  cvp x           = d_in[0];
  cvp E_emb       = d_in[1];
  const int* ei   = (const int*)d_in[2];
  cvp node_proj   = d_in[3];
  cvp emb_proj    = d_in[4];
  cvp conv_w0     = d_in[5];
  cvp conv_w1     = d_in[6];
  cvp conv_b      = d_in[7];
  cvp lin2_w      = d_in[8];
  cvp lin2_b      = d_in[9];
  cvp masked_proj = d_in[10];
  cvp normal_proj = d_in[11];
  cvp g1_wl       = d_in[12];
  cvp g1_bl       = d_in[13];
  cvp g1_wr       = d_in[14];
  cvp g1_br       = d_in[15];
  cvp g1_att      = d_in[16];
  cvp g1_bias     = d_in[17];
  cvp g2_wl       = d_in[18];
  cvp g2_bl       = d_in[19];
  cvp g2_wr       = d_in[20];
  cvp g2_br       = d_in[21];
  cvp g2_att      = d_in[22];
  cvp g2_bias     = d_in[23];
  cvp rec_w       = d_in[24];
  cvp rec_b       = d_in[25];
  const int E = in_sizes[2] / 2;

  k_detect<<<1, 256, 0, stream>>>(x, in_sizes[0]);
  k_dense<<<NN, 128, 0, stream>>>(x, E_emb, node_proj, emb_proj,
      conv_w0, conv_w1, conv_b, lin2_w, lin2_b, masked_proj, normal_proj,
      g1_wl, g1_bl, g1_wr, g1_br);
  k_csr<<<1, NN, 0, stream>>>(ei, E);
  k_l1base<<<NN, 128, 0, stream>>>(g1_att, g1_bias, g2_wl, g2_bl);
  k_periter<<<NN, 256, 0, stream>>>(g1_att, g1_bias, g2_wl, g2_bl, g2_wr, g2_br,
      g2_att, g2_bias, rec_w, rec_b, d_out);
}

// Round 3
// 235.622 us; speedup vs baseline: 1.2605x; 1.2605x over previous
//
#include <hip/hip_runtime.h>
#include <hip/hip_bf16.h>

// NodeDetector: per-node-masked 2-layer GATv2 forward, delta formulation.
// N=256 nodes, C2=64, H=2 heads, E=4352 edges (incl. self loops).
// Only row i of `proj` changes per mask iteration i. Layer-2 output is read
// only at node i, whose in-sources' xl2 values change only for sources that
// are themselves layer-1-affected. Affected = {i} ∪ out-nbrs(i); needed for
// layer 2 = {i} ∪ (out-nbrs(i) ∩ in-nbrs(i))  — ~2.5 nodes avg, not ~17.
// R3: needed-set pruning in k_periter (110us -> ~30us predicted) + merged
// detect/csr launch.

#define NN 256
#define EDGE_CAP 96   // max in-degree supported (actual max ~35)
#define E2_CAP 64     // max in-degree for layer-2 edge buffer
#define E_CAP 6144    // max edges (actual 4352)
#define A_CAP 32      // max needed-set size (actual ~2-6)

// ---- persistent device-global scratch ----
__device__ float g_xl0[NN*128], g_xr0[NN*128], g_xlV[NN*128], g_xrV[NN*128];
__device__ float g_g1_0[NN*64], g_xl2_0[NN*128];
__device__ int   g_in_ptr[NN+1], g_out_ptr[NN+1];
__device__ int   g_in_src[E_CAP], g_out_dst[E_CAP];
__device__ int   g_f32;   // 1 => float32 inputs/output, 0 => bf16

typedef const void* cvp;
__device__ __forceinline__ float b2f(__hip_bfloat16 v) { return __bfloat162float(v); }
// uniform-predicate dual-dtype load (f loop-invariant => compiler unswitches)
__device__ __forceinline__ float ldin(cvp p, int i, int f) {
  if (f) return ((const float*)p)[i];
  return b2f(((const __hip_bfloat16*)p)[i]);
}

// ---------------------------------------------------------------------------
// K0: dtype detection + CSR build, one block.
// Detection: f32 data misread as bf16 -> ~half of elements decode to |v|>16
// or NaN; genuine bf16 N(0,1) data has none.
// ---------------------------------------------------------------------------
__global__ __launch_bounds__(256) void k_init(cvp x, int n,
                                              const int* __restrict__ ei, int E)
{
  __shared__ int cnt;
  __shared__ int cin[NN], cou[NN], pin[NN+1], pou[NN+1];
  const int t = threadIdx.x;
  if (E > E_CAP) E = E_CAP;
  if (t == 0) cnt = 0;
  cin[t] = 0; cou[t] = 0;
  __syncthreads();
  // --- dtype detect ---
  {
    const __hip_bfloat16* xb = (const __hip_bfloat16*)x;
    const int lim = n < 4096 ? n : 4096;
    int c = 0;
    for (int i = t; i < lim; i += 256) {
      const float v = b2f(xb[i]);
      if (!(fabsf(v) <= 16.f)) c++;   // counts NaN too
    }
    if (c) atomicAdd(&cnt, c);
  }
  // --- degree count ---
  for (int e = t; e < E; e += 256) {
    atomicAdd(&cin[ei[E+e] & (NN-1)], 1);
    atomicAdd(&cou[ei[e]   & (NN-1)], 1);
  }
  __syncthreads();
  if (t == 0) {
    g_f32 = (cnt > 64) ? 1 : 0;
    int si = 0, so = 0;
    for (int nn = 0; nn < NN; ++nn) { pin[nn] = si; si += cin[nn]; pou[nn] = so; so += cou[nn]; }
    pin[NN] = si; pou[NN] = so;
  }
  __syncthreads();
  g_in_ptr[t] = pin[t]; g_out_ptr[t] = pou[t];
  if (t == 0) { g_in_ptr[NN] = pin[NN]; g_out_ptr[NN] = pou[NN]; }
  cin[t] = pin[t]; cou[t] = pou[t];
  __syncthreads();
  for (int e = t; e < E; e += 256) {
    const int s = ei[e] & (NN-1), d = ei[E+e] & (NN-1);
    g_in_src[atomicAdd(&cin[d], 1)] = s;
    g_out_dst[atomicAdd(&cou[s], 1)] = d;
  }
}

// ---------------------------------------------------------------------------
// K1: shared dense precompute. One block per node j (128 threads).
// Produces xl0/xr0 (baseline GATv2-1 transforms) and xlV/xrV (the values row i
// takes when it is the masked node).
// ---------------------------------------------------------------------------
__global__ __launch_bounds__(128) void k_dense(
    cvp x, cvp E_emb, cvp node_proj, cvp emb_proj,
    cvp conv_w0, cvp conv_w1, cvp conv_b,
    cvp lin2_w, cvp lin2_b, cvp masked_proj, cvp normal_proj,
    cvp g1_wl, cvp g1_bl, cvp g1_wr, cvp g1_br)
{
  const int j = blockIdx.x, t = threadIdx.x;
  const int f = g_f32;
  __shared__ float sx[64], sE[64], sxp[128], sEp[128], sh0[128], shm[128],
                   sm0[64], sMm[64], sp0[64], sV[64];
  if (t < 64) { sx[t] = ldin(x, j*64+t, f); sE[t] = ldin(E_emb, j*64+t, f); }
  __syncthreads();
  float a = 0.f, b = 0.f;
  for (int k = 0; k < 64; ++k) {
    a += sx[k] * ldin(node_proj, k*128+t, f);
    b += sE[k] * ldin(emb_proj,  k*128+t, f);
  }
  sxp[t] = a; sEp[t] = b;
  __syncthreads();
  float xw1 = 0.f, ew0 = 0.f;
  for (int k = 0; k < 128; ++k) {
    xw1 += sxp[k] * ldin(conv_w1, k*128+t, f);
    ew0 += sEp[k] * ldin(conv_w0, k*128+t, f);
  }
  const float cb = ldin(conv_b, t, f);
  sh0[t] = tanhf(ew0 + xw1 + cb);
  shm[t] = tanhf(ew0 + cb);
  __syncthreads();
  if (t < 64) {
    float m0 = ldin(lin2_b, t, f), Mm = m0;
    for (int k = 0; k < 128; ++k) {
      const float w = ldin(lin2_w, k*64+t, f);
      m0 += sh0[k]*w; Mm += shm[k]*w;
    }
    sm0[t] = m0; sMm[t] = Mm;
  }
  __syncthreads();
  if (t < 64) {
    float p = 0.f, v = 0.f;
    for (int k = 0; k < 64; ++k) {
      p += sm0[k] * ldin(normal_proj, k*64+t, f);
      v += sMm[k] * ldin(masked_proj, k*64+t, f);
    }
    sp0[t] = p; sV[t] = v;
  }
  __syncthreads();
  float l0 = ldin(g1_bl, t, f), r0 = ldin(g1_br, t, f);
  float lV = l0, rV = r0;
  for (int k = 0; k < 64; ++k) {
    const float wl = ldin(g1_wl, k*128+t, f), wr = ldin(g1_wr, k*128+t, f);
    l0 += sp0[k]*wl; r0 += sp0[k]*wr;
    lV += sV[k]*wl;  rV += sV[k]*wr;
  }
  g_xl0[j*128+t] = l0; g_xr0[j*128+t] = r0;
  g_xlV[j*128+t] = lV; g_xrV[j*128+t] = rV;
}

// ---------------------------------------------------------------------------
// K2: baseline layer-1 attention -> g1_0, and xl2_0 = elu-out @ g2_wl + g2_bl.
// One block per node j (128 threads = 2 waves).
// ---------------------------------------------------------------------------
__global__ __launch_bounds__(128) void k_l1base(
    cvp g1_att, cvp g1_bias, cvp g2_wl, cvp g2_bl)
{
  const int j = blockIdx.x, t = threadIdx.x;
  const int f = g_f32;
  __shared__ float sxr[128], satt[128], slog[2][EDGE_CAP], sw[2][EDGE_CAP];
  __shared__ float sinv[2], sagg[128], sg1[64];
  __shared__ int ssrc[EDGE_CAP];
  const int base = g_in_ptr[j];
  int nE = g_in_ptr[j+1] - base;
  if (nE > EDGE_CAP) nE = EDGE_CAP;
  sxr[t] = g_xr0[j*128+t];
  satt[t] = ldin(g1_att, t, f);
  for (int e = t; e < nE; e += 128) ssrc[e] = g_in_src[base+e];
  __syncthreads();
  for (int idx = t; idx < nE*2; idx += 128) {
    const int e = idx >> 1, h = idx & 1, s = ssrc[e];
    const float* xls = g_xl0 + s*128 + h*64;
    float acc = 0.f;
    for (int c = 0; c < 64; ++c) {
      float v = xls[c] + sxr[h*64+c];
      v = v > 0.f ? v : 0.2f*v;
      acc += satt[h*64+c]*v;
    }
    slog[h][e] = acc;
  }
  __syncthreads();
  {
    const int h = t >> 6, lane = t & 63;
    float m = -1e30f;
    for (int e = lane; e < nE; e += 64) m = fmaxf(m, slog[h][e]);
    for (int o = 1; o < 64; o <<= 1) m = fmaxf(m, __shfl_xor(m, o));
    float ssum = 0.f;
    for (int e = lane; e < nE; e += 64) { const float w = __expf(slog[h][e]-m); sw[h][e] = w; ssum += w; }
    for (int o = 1; o < 64; o <<= 1) ssum += __shfl_xor(ssum, o);
    if (lane == 0) sinv[h] = 1.f/(ssum + 1e-16f);
  }
  __syncthreads();
  {
    const int h = t >> 6, c = t & 63;
    float acc = 0.f;
    for (int e = 0; e < nE; ++e) acc += sw[h][e]*g_xl0[ssrc[e]*128 + h*64 + c];
    sagg[t] = acc*sinv[h];
  }
  __syncthreads();
  if (t < 64) {
    float g = 0.5f*(sagg[t]+sagg[64+t]) + ldin(g1_bias, t, f);
    g = g > 0.f ? g : expm1f(g);
    sg1[t] = g; g_g1_0[j*64+t] = g;
  }
  __syncthreads();
  float acc = ldin(g2_bl, t, f);
  for (int k = 0; k < 64; ++k) acc += sg1[k]*ldin(g2_wl, k*128+t, f);
  g_xl2_0[j*128+t] = acc;
}

// ---------------------------------------------------------------------------
// K3: per-mask-iteration kernel. Block i handles mask position i:
//   needed set = {i} ∪ (out-nbrs(i) ∩ in-nbrs(i))   [~2.5 nodes avg]
//   1. recompute layer-1 at each needed node with row i's xl/xr -> V-values
//   2. layer-2 attention at node i only; reconstruction head; tanh; output
// ---------------------------------------------------------------------------
__global__ __launch_bounds__(256) void k_periter(
    cvp g1_att, cvp g1_bias, cvp g2_wl, cvp g2_bl, cvp g2_wr, cvp g2_br,
    cvp g2_att, cvp g2_bias, cvp rec_w, cvp rec_b, void* out)
{
  const int i = blockIdx.x, t = threadIdx.x;
  const int f = g_f32;
  __shared__ int slotOf[NN];            // node -> slot in g1n, or -1
  __shared__ unsigned char isInN[NN];   // in-neighbor-of-i bitmap
  __shared__ int listA[A_CAP];
  __shared__ int nA;
  __shared__ float g1n[A_CAP*64];       // recomputed layer-1 outputs
  __shared__ float xl2e[E2_CAP*128];
  __shared__ float satt[128], satt2[128];
  __shared__ int ssrc[EDGE_CAP], ssrc2[E2_CAP];
  __shared__ float slog[2][EDGE_CAP], sw[2][EDGE_CAP], sinv[2], sagg[128];
  __shared__ float sxr[128], xr2i[128], sg[64];

  if (t < NN) { slotOf[t] = -1; isInN[t] = 0; }
  if (t == 0) { nA = 1; listA[0] = i; }
  if (t < 128) { satt[t] = ldin(g1_att, t, f); satt2[t] = ldin(g2_att, t, f); }
  __syncthreads();
  if (t == 0) slotOf[i] = 0;

  // ---- in-edges of i (also needed for layer 2) + in-neighbor bitmap ----
  const int b2 = g_in_ptr[i];
  int nE2 = g_in_ptr[i+1] - b2;
  if (nE2 > E2_CAP) nE2 = E2_CAP;
  for (int e = t; e < nE2; e += 256) {
    const int s = g_in_src[b2+e];
    ssrc2[e] = s;
    isInN[s] = 1;
  }
  __syncthreads();

  // ---- needed set: mutual neighbors of i ----
  const int ob = g_out_ptr[i], onE = g_out_ptr[i+1] - ob;
  for (int e = t; e < onE; e += 256) {
    const int d = g_out_dst[ob+e];
    if (d != i && isInN[d]) {
      if (atomicCAS(&slotOf[d], -1, -2) == -1) {
        const int p = atomicAdd(&nA, 1);
        if (p < A_CAP) { listA[p] = d; slotOf[d] = p; }
        else slotOf[d] = -1;   // overflow: fall back to baseline (won't happen)
      }
    }
  }
  __syncthreads();
  int nAl = nA; if (nAl > A_CAP) nAl = A_CAP;

  // ---- recompute layer-1 at each needed node ----
  for (int a = 0; a < nAl; ++a) {
    const int j = listA[a];
    const int base = g_in_ptr[j];
    int nE = g_in_ptr[j+1] - base;
    if (nE > EDGE_CAP) nE = EDGE_CAP;
    if (t < 128) sxr[t] = (j == i) ? g_xrV[i*128+t] : g_xr0[j*128+t];
    for (int e = t; e < nE; e += 256) ssrc[e] = g_in_src[base+e];
    __syncthreads();
    for (int idx = t; idx < nE*2; idx += 256) {
      const int e = idx >> 1, h = idx & 1, s = ssrc[e];
      const float* xls = ((s == i) ? g_xlV : g_xl0) + s*128 + h*64;
      float acc = 0.f;
      for (int c = 0; c < 64; ++c) {
        float v = xls[c] + sxr[h*64+c];
        v = v > 0.f ? v : 0.2f*v;
        acc += satt[h*64+c]*v;
      }
      slog[h][e] = acc;
    }
    __syncthreads();
    if (t < 128) {
      const int h = t >> 6, lane = t & 63;
      float m = -1e30f;
      for (int e = lane; e < nE; e += 64) m = fmaxf(m, slog[h][e]);
      for (int o = 1; o < 64; o <<= 1) m = fmaxf(m, __shfl_xor(m, o));
      float ssum = 0.f;
      for (int e = lane; e < nE; e += 64) { const float w = __expf(slog[h][e]-m); sw[h][e] = w; ssum += w; }
      for (int o = 1; o < 64; o <<= 1) ssum += __shfl_xor(ssum, o);
      if (lane == 0) sinv[h] = 1.f/(ssum + 1e-16f);
    }
    __syncthreads();
    if (t < 128) {
      const int h = t >> 6, c = t & 63;
      float acc = 0.f;
      for (int e = 0; e < nE; ++e) {
        const int s = ssrc[e];
        const float* xls = ((s == i) ? g_xlV : g_xl0) + s*128;
        acc += sw[h][e]*xls[h*64+c];
      }
      sagg[t] = acc*sinv[h];
    }
    __syncthreads();
    if (t < 64) {
      float g = 0.5f*(sagg[t]+sagg[64+t]) + ldin(g1_bias, t, f);
      g = g > 0.f ? g : expm1f(g);
      g1n[a*64+t] = g;
    }
    __syncthreads();
  }

  // ---- layer 2 at node i ----
  // per-edge xl2: changed sources recomputed, others from precompute
  for (int idx = t; idx < nE2*128; idx += 256) {
    const int e = idx >> 7, c = idx & 127, s = ssrc2[e];
    const int sl = slotOf[s];
    float v;
    if (sl >= 0) {
      v = ldin(g2_bl, c, f);
      const float* g1r = g1n + sl*64;
      for (int k = 0; k < 64; ++k) v += g1r[k]*ldin(g2_wl, k*128+c, f);
    } else {
      v = g_xl2_0[s*128+c];
    }
    xl2e[e*128+c] = v;
  }
  if (t < 128) {
    float v = ldin(g2_br, t, f);
    const float* g1r = g1n;          // slot 0 == node i
    for (int k = 0; k < 64; ++k) v += g1r[k]*ldin(g2_wr, k*128+t, f);
    xr2i[t] = v;
  }
  __syncthreads();
  for (int idx = t; idx < nE2*2; idx += 256) {
    const int e = idx >> 1, h = idx & 1;
    const float* xle = xl2e + e*128 + h*64;
    float acc = 0.f;
    for (int c = 0; c < 64; ++c) {
      float v = xle[c] + xr2i[h*64+c];
      v = v > 0.f ? v : 0.2f*v;
      acc += satt2[h*64+c]*v;
    }
    slog[h][e] = acc;
  }
  __syncthreads();
  if (t < 128) {
    const int h = t >> 6, lane = t & 63;
    float m = -1e30f;
    for (int e = lane; e < nE2; e += 64) m = fmaxf(m, slog[h][e]);
    for (int o = 1; o < 64; o <<= 1) m = fmaxf(m, __shfl_xor(m, o));
    float ssum = 0.f;
    for (int e = lane; e < nE2; e += 64) { const float w = __expf(slog[h][e]-m); sw[h][e] = w; ssum += w; }
    for (int o = 1; o < 64; o <<= 1) ssum += __shfl_xor(ssum, o);
    if (lane == 0) sinv[h] = 1.f/(ssum + 1e-16f);
  }
  __syncthreads();
  if (t < 128) {
    const int h = t >> 6, c = t & 63;
    float acc = 0.f;
    for (int e = 0; e < nE2; ++e) acc += sw[h][e]*xl2e[e*128 + h*64 + c];
    sagg[t] = acc*sinv[h];
  }
  __syncthreads();
  if (t < 64) {
    float g = 0.5f*(sagg[t]+sagg[64+t]) + ldin(g2_bias, t, f);
    g = g > 0.f ? g : expm1f(g);
    sg[t] = g;
  }
  __syncthreads();
  if (t < 64) {
    float v = ldin(rec_b, t, f);
    for (int c = 0; c < 64; ++c) v += sg[c]*ldin(rec_w, c*64+t, f);
    const float r = tanhf(v);
    if (f) ((float*)out)[i*64+t] = r;
    else   ((__hip_bfloat16*)out)[i*64+t] = __float2bfloat16(r);
  }
}

// ---------------------------------------------------------------------------
extern "C" void kernel_launch(void* const* d_in, const int* in_sizes, int n_in,
                              void* d_out, int out_size, void* d_ws, size_t ws_size,
                              hipStream_t stream)
{
  cvp x           = d_in[0];
  cvp E_emb       = d_in[1];
  const int* ei   = (const int*)d_in[2];
  cvp node_proj   = d_in[3];
  cvp emb_proj    = d_in[4];
  cvp conv_w0     = d_in[5];
  cvp conv_w1     = d_in[6];
  cvp conv_b      = d_in[7];
  cvp lin2_w      = d_in[8];
  cvp lin2_b      = d_in[9];
  cvp masked_proj = d_in[10];
  cvp normal_proj = d_in[11];
  cvp g1_wl       = d_in[12];
  cvp g1_bl       = d_in[13];
  cvp g1_wr       = d_in[14];
  cvp g1_br       = d_in[15];
  cvp g1_att      = d_in[16];
  cvp g1_bias     = d_in[17];
  cvp g2_wl       = d_in[18];
  cvp g2_bl       = d_in[19];
  cvp g2_wr       = d_in[20];
  cvp g2_br       = d_in[21];
  cvp g2_att      = d_in[22];
  cvp g2_bias     = d_in[23];
  cvp rec_w       = d_in[24];
  cvp rec_b       = d_in[25];
  const int E = in_sizes[2] / 2;

  k_init<<<1, 256, 0, stream>>>(x, in_sizes[0], ei, E);
  k_dense<<<NN, 128, 0, stream>>>(x, E_emb, node_proj, emb_proj,
      conv_w0, conv_w1, conv_b, lin2_w, lin2_b, masked_proj, normal_proj,
      g1_wl, g1_bl, g1_wr, g1_br);
  k_l1base<<<NN, 128, 0, stream>>>(g1_att, g1_bias, g2_wl, g2_bl);
  k_periter<<<NN, 256, 0, stream>>>(g1_att, g1_bias, g2_wl, g2_bl, g2_wr, g2_br,
      g2_att, g2_bias, rec_w, rec_b, d_out);
}

// Round 4
// 186.434 us; speedup vs baseline: 1.5930x; 1.2638x over previous
//
#include <hip/hip_runtime.h>
#include <hip/hip_bf16.h>

// NodeDetector: per-node-masked 2-layer GATv2 forward, delta formulation.
// N=256 nodes, C2=64, H=2 heads, E=4352 edges (incl. self loops).
// Only row i of `proj` changes per mask iteration i. Layer-2 output is read
// only at node i => needed recompute set = {i} ∪ (out-nbrs(i) ∩ in-nbrs(i)),
// ~2.5 nodes avg.
// R4: kill the per-element dtype branch (R3 showed VGPR=20 => no load
// pipelining). k_init now also converts ALL inputs to f32 into g_w once;
// compute kernels are branch-free f32 so the compiler can unroll.

#define NN 256
#define EDGE_CAP 96   // max in-degree supported (actual max ~35)
#define E2_CAP 64     // max in-degree for layer-2 edge buffer
#define E_CAP 6144    // max edges (actual 4352)
#define A_CAP 32      // max needed-set size (actual ~2-6)

// ---- converted-input arena offsets (floats) ----
#define OFF_X      0
#define OFF_E      16384
#define OFF_NP     32768
#define OFF_EP     40960
#define OFF_CW0    49152
#define OFF_CW1    65536
#define OFF_CB     81920
#define OFF_L2W    82048
#define OFF_L2B    90240
#define OFF_MP     90304
#define OFF_NPJ    94400
#define OFF_G1WL   98496
#define OFF_G1BL   106688
#define OFF_G1WR   106816
#define OFF_G1BR   115008
#define OFF_G1ATT  115136
#define OFF_G1BIAS 115264
#define OFF_G2WL   115328
#define OFF_G2BL   123520
#define OFF_G2WR   123648
#define OFF_G2BR   131840
#define OFF_G2ATT  131968
#define OFF_G2BIAS 132096
#define OFF_RECW   132160
#define OFF_RECB   136256
#define W_TOTAL    136320

// ---- persistent device-global scratch ----
__device__ float g_w[W_TOTAL];
__device__ float g_xl0[NN*128], g_xr0[NN*128], g_xlV[NN*128], g_xrV[NN*128];
__device__ float g_xl2_0[NN*128];
__device__ int   g_in_ptr[NN+1], g_out_ptr[NN+1];
__device__ int   g_in_src[E_CAP], g_out_dst[E_CAP];
__device__ int   g_f32;   // 1 => float32 inputs/output, 0 => bf16

// converter block -> (segment, 4096-chunk) static mapping (44 blocks)
__device__ const int c_off[26] = {
  0,16384,32768,40960,49152,65536,81920,82048,90240,90304,94400,98496,
  106688,106816,115008,115136,115264,115328,123520,123648,131840,131968,
  132096,132160,136256,136320};
__device__ const signed char c_seg[44] = {
  0,0,0,0, 1,1,1,1, 2,2, 3,3, 4,4,4,4, 5,5,5,5, 6, 7,7, 8, 9, 10,
  11,11, 12, 13,13, 14, 15, 16, 17,17, 18, 19,19, 20, 21, 22, 23, 24};
__device__ const signed char c_sub[44] = {
  0,1,2,3, 0,1,2,3, 0,1, 0,1, 0,1,2,3, 0,1,2,3, 0, 0,1, 0, 0, 0,
  0,1, 0, 0,1, 0, 0, 0, 0,1, 0, 0,1, 0, 0, 0, 0, 0};

typedef const void* cvp;
__device__ __forceinline__ float b2f(__hip_bfloat16 v) { return __bfloat162float(v); }

__device__ __forceinline__ cvp pick_seg(int s,
    cvp p0, cvp p1, cvp p2, cvp p3, cvp p4, cvp p5, cvp p6, cvp p7, cvp p8,
    cvp p9, cvp p10, cvp p11, cvp p12, cvp p13, cvp p14, cvp p15, cvp p16,
    cvp p17, cvp p18, cvp p19, cvp p20, cvp p21, cvp p22, cvp p23, cvp p24)
{
  switch (s) {
    case 0: return p0;   case 1: return p1;   case 2: return p2;
    case 3: return p3;   case 4: return p4;   case 5: return p5;
    case 6: return p6;   case 7: return p7;   case 8: return p8;
    case 9: return p9;   case 10: return p10; case 11: return p11;
    case 12: return p12; case 13: return p13; case 14: return p14;
    case 15: return p15; case 16: return p16; case 17: return p17;
    case 18: return p18; case 19: return p19; case 20: return p20;
    case 21: return p21; case 22: return p22; case 23: return p23;
    default: return p24;
  }
}

// ---------------------------------------------------------------------------
// K0: 45 blocks. Every block first detects input dtype from x (f32 data
// misread as bf16 -> ~half of elements decode to |v|>16 or NaN; bf16 N(0,1)
// data has none). Blocks 0..43 then convert their assigned 4096-element chunk
// of one input into the f32 arena g_w; block 44 builds the CSR + publishes
// g_f32 for the epilogue store.
// ---------------------------------------------------------------------------
__global__ __launch_bounds__(256) void k_init(
    cvp x, cvp E_emb, cvp node_proj, cvp emb_proj,
    cvp conv_w0, cvp conv_w1, cvp conv_b, cvp lin2_w, cvp lin2_b,
    cvp masked_proj, cvp normal_proj,
    cvp g1_wl, cvp g1_bl, cvp g1_wr, cvp g1_br, cvp g1_att, cvp g1_bias,
    cvp g2_wl, cvp g2_bl, cvp g2_wr, cvp g2_br, cvp g2_att, cvp g2_bias,
    cvp rec_w, cvp rec_b,
    int n, const int* __restrict__ ei, int E)
{
  const int t = threadIdx.x, b = blockIdx.x;
  __shared__ int cnt;
  if (t == 0) cnt = 0;
  __syncthreads();
  {
    const __hip_bfloat16* xb = (const __hip_bfloat16*)x;
    const int lim = n < 4096 ? n : 4096;
    int c = 0;
    for (int i = t; i < lim; i += 256) {
      const float v = b2f(xb[i]);
      if (!(fabsf(v) <= 16.f)) c++;   // counts NaN too
    }
    if (c) atomicAdd(&cnt, c);
  }
  __syncthreads();
  const int f = (cnt > 64) ? 1 : 0;

  if (b < 44) {
    // ---- convert one 4096-chunk ----
    const int s = c_seg[b];
    cvp p = pick_seg(s, x, E_emb, node_proj, emb_proj, conv_w0, conv_w1,
                     conv_b, lin2_w, lin2_b, masked_proj, normal_proj,
                     g1_wl, g1_bl, g1_wr, g1_br, g1_att, g1_bias,
                     g2_wl, g2_bl, g2_wr, g2_br, g2_att, g2_bias,
                     rec_w, rec_b);
    const int off = c_off[s];
    const int base = (int)c_sub[b] * 4096;
    int lim = (c_off[s+1] - off) - base;
    if (lim > 4096) lim = 4096;
    if (f) {
      const float* pf = (const float*)p;
      for (int i = t; i < lim; i += 256) g_w[off+base+i] = pf[base+i];
    } else {
      const __hip_bfloat16* pb = (const __hip_bfloat16*)p;
      for (int i = t; i < lim; i += 256) g_w[off+base+i] = b2f(pb[base+i]);
    }
    return;
  }

  // ---- block 44: publish dtype + CSR build ----
  __shared__ int cin[NN], cou[NN], pin[NN+1], pou[NN+1];
  if (E > E_CAP) E = E_CAP;
  if (t == 0) g_f32 = f;
  cin[t] = 0; cou[t] = 0;
  __syncthreads();
  for (int e = t; e < E; e += 256) {
    atomicAdd(&cin[ei[E+e] & (NN-1)], 1);
    atomicAdd(&cou[ei[e]   & (NN-1)], 1);
  }
  __syncthreads();
  if (t == 0) {
    int si = 0, so = 0;
    for (int nn = 0; nn < NN; ++nn) { pin[nn] = si; si += cin[nn]; pou[nn] = so; so += cou[nn]; }
    pin[NN] = si; pou[NN] = so;
  }
  __syncthreads();
  g_in_ptr[t] = pin[t]; g_out_ptr[t] = pou[t];
  if (t == 0) { g_in_ptr[NN] = pin[NN]; g_out_ptr[NN] = pou[NN]; }
  cin[t] = pin[t]; cou[t] = pou[t];
  __syncthreads();
  for (int e = t; e < E; e += 256) {
    const int s = ei[e] & (NN-1), d = ei[E+e] & (NN-1);
    g_in_src[atomicAdd(&cin[d], 1)] = s;
    g_out_dst[atomicAdd(&cou[s], 1)] = d;
  }
}

// ---------------------------------------------------------------------------
// K1: shared dense precompute. One block per node j (128 threads), pure f32.
// ---------------------------------------------------------------------------
__global__ __launch_bounds__(128) void k_dense()
{
  const int j = blockIdx.x, t = threadIdx.x;
  __shared__ float sx[64], sE[64], sxp[128], sEp[128], sh0[128], shm[128],
                   sm0[64], sMm[64], sp0[64], sV[64];
  if (t < 64) { sx[t] = g_w[OFF_X + j*64+t]; sE[t] = g_w[OFF_E + j*64+t]; }
  __syncthreads();
  float a = 0.f, b = 0.f;
  #pragma unroll
  for (int k = 0; k < 64; ++k) {
    a += sx[k] * g_w[OFF_NP + k*128+t];
    b += sE[k] * g_w[OFF_EP + k*128+t];
  }
  sxp[t] = a; sEp[t] = b;
  __syncthreads();
  float xw1 = 0.f, ew0 = 0.f;
  #pragma unroll
  for (int k = 0; k < 128; ++k) {
    xw1 += sxp[k] * g_w[OFF_CW1 + k*128+t];
    ew0 += sEp[k] * g_w[OFF_CW0 + k*128+t];
  }
  const float cb = g_w[OFF_CB + t];
  sh0[t] = tanhf(ew0 + xw1 + cb);
  shm[t] = tanhf(ew0 + cb);
  __syncthreads();
  if (t < 64) {
    float m0 = g_w[OFF_L2B + t], Mm = m0;
    #pragma unroll
    for (int k = 0; k < 128; ++k) {
      const float w = g_w[OFF_L2W + k*64+t];
      m0 += sh0[k]*w; Mm += shm[k]*w;
    }
    sm0[t] = m0; sMm[t] = Mm;
  }
  __syncthreads();
  if (t < 64) {
    float p = 0.f, v = 0.f;
    #pragma unroll
    for (int k = 0; k < 64; ++k) {
      p += sm0[k] * g_w[OFF_NPJ + k*64+t];
      v += sMm[k] * g_w[OFF_MP + k*64+t];
    }
    sp0[t] = p; sV[t] = v;
  }
  __syncthreads();
  float l0 = g_w[OFF_G1BL + t], r0 = g_w[OFF_G1BR + t];
  float lV = l0, rV = r0;
  #pragma unroll
  for (int k = 0; k < 64; ++k) {
    const float wl = g_w[OFF_G1WL + k*128+t], wr = g_w[OFF_G1WR + k*128+t];
    l0 += sp0[k]*wl; r0 += sp0[k]*wr;
    lV += sV[k]*wl;  rV += sV[k]*wr;
  }
  g_xl0[j*128+t] = l0; g_xr0[j*128+t] = r0;
  g_xlV[j*128+t] = lV; g_xrV[j*128+t] = rV;
}

// ---------------------------------------------------------------------------
// K2: baseline layer-1 attention -> xl2_0 = elu(mean-head) @ g2_wl + g2_bl.
// One block per node j (128 threads = 2 waves).
// ---------------------------------------------------------------------------
__global__ __launch_bounds__(128) void k_l1base()
{
  const int j = blockIdx.x, t = threadIdx.x;
  __shared__ float sxr[128], satt[128], slog[2][EDGE_CAP], sw[2][EDGE_CAP];
  __shared__ float sinv[2], sagg[128], sg1[64];
  __shared__ int ssrc[EDGE_CAP];
  const int base = g_in_ptr[j];
  int nE = g_in_ptr[j+1] - base;
  if (nE > EDGE_CAP) nE = EDGE_CAP;
  sxr[t] = g_xr0[j*128+t];
  satt[t] = g_w[OFF_G1ATT + t];
  for (int e = t; e < nE; e += 128) ssrc[e] = g_in_src[base+e];
  __syncthreads();
  for (int idx = t; idx < nE*2; idx += 128) {
    const int e = idx >> 1, h = idx & 1, s = ssrc[e];
    const float* xls = g_xl0 + s*128 + h*64;
    float acc = 0.f;
    #pragma unroll
    for (int c = 0; c < 64; ++c) {
      float v = xls[c] + sxr[h*64+c];
      v = v > 0.f ? v : 0.2f*v;
      acc += satt[h*64+c]*v;
    }
    slog[h][e] = acc;
  }
  __syncthreads();
  {
    const int h = t >> 6, lane = t & 63;
    float m = -1e30f;
    for (int e = lane; e < nE; e += 64) m = fmaxf(m, slog[h][e]);
    for (int o = 1; o < 64; o <<= 1) m = fmaxf(m, __shfl_xor(m, o));
    float ssum = 0.f;
    for (int e = lane; e < nE; e += 64) { const float w = __expf(slog[h][e]-m); sw[h][e] = w; ssum += w; }
    for (int o = 1; o < 64; o <<= 1) ssum += __shfl_xor(ssum, o);
    if (lane == 0) sinv[h] = 1.f/(ssum + 1e-16f);
  }
  __syncthreads();
  {
    const int h = t >> 6, c = t & 63;
    float acc = 0.f;
    for (int e = 0; e < nE; ++e) acc += sw[h][e]*g_xl0[ssrc[e]*128 + h*64 + c];
    sagg[t] = acc*sinv[h];
  }
  __syncthreads();
  if (t < 64) {
    float g = 0.5f*(sagg[t]+sagg[64+t]) + g_w[OFF_G1BIAS + t];
    g = g > 0.f ? g : expm1f(g);
    sg1[t] = g;
  }
  __syncthreads();
  float acc = g_w[OFF_G2BL + t];
  #pragma unroll
  for (int k = 0; k < 64; ++k) acc += sg1[k]*g_w[OFF_G2WL + k*128+t];
  g_xl2_0[j*128+t] = acc;
}

// ---------------------------------------------------------------------------
// K3: per-mask-iteration kernel. Block i handles mask position i:
//   needed set = {i} ∪ (out-nbrs(i) ∩ in-nbrs(i))   [~2.5 nodes avg]
//   1. recompute layer-1 at each needed node with row i's xl/xr -> V-values
//   2. layer-2 attention at node i only; reconstruction head; tanh; output
// ---------------------------------------------------------------------------
__global__ __launch_bounds__(256) void k_periter(void* out)
{
  const int i = blockIdx.x, t = threadIdx.x;
  __shared__ int slotOf[NN];            // node -> slot in g1n, or -1
  __shared__ unsigned char isInN[NN];   // in-neighbor-of-i bitmap
  __shared__ int listA[A_CAP];
  __shared__ int nA;
  __shared__ float g1n[A_CAP*64];       // recomputed layer-1 outputs
  __shared__ float xl2e[E2_CAP*128];
  __shared__ float satt[128], satt2[128];
  __shared__ int ssrc[EDGE_CAP], ssrc2[E2_CAP];
  __shared__ float slog[2][EDGE_CAP], sw[2][EDGE_CAP], sinv[2], sagg[128];
  __shared__ float sxr[128], xr2i[128], sg[64];

  if (t < NN) { slotOf[t] = -1; isInN[t] = 0; }
  if (t == 0) { nA = 1; listA[0] = i; }
  if (t < 128) { satt[t] = g_w[OFF_G1ATT + t]; satt2[t] = g_w[OFF_G2ATT + t]; }
  __syncthreads();
  if (t == 0) slotOf[i] = 0;

  // ---- in-edges of i (also needed for layer 2) + in-neighbor bitmap ----
  const int b2 = g_in_ptr[i];
  int nE2 = g_in_ptr[i+1] - b2;
  if (nE2 > E2_CAP) nE2 = E2_CAP;
  for (int e = t; e < nE2; e += 256) {
    const int s = g_in_src[b2+e];
    ssrc2[e] = s;
    isInN[s] = 1;
  }
  __syncthreads();

  // ---- needed set: mutual neighbors of i ----
  const int ob = g_out_ptr[i], onE = g_out_ptr[i+1] - ob;
  for (int e = t; e < onE; e += 256) {
    const int d = g_out_dst[ob+e];
    if (d != i && isInN[d]) {
      if (atomicCAS(&slotOf[d], -1, -2) == -1) {
        const int p = atomicAdd(&nA, 1);
        if (p < A_CAP) { listA[p] = d; slotOf[d] = p; }
        else slotOf[d] = -1;   // overflow: fall back to baseline (won't happen)
      }
    }
  }
  __syncthreads();
  int nAl = nA; if (nAl > A_CAP) nAl = A_CAP;

  // ---- recompute layer-1 at each needed node ----
  for (int a = 0; a < nAl; ++a) {
    const int j = listA[a];
    const int base = g_in_ptr[j];
    int nE = g_in_ptr[j+1] - base;
    if (nE > EDGE_CAP) nE = EDGE_CAP;
    if (t < 128) sxr[t] = (j == i) ? g_xrV[i*128+t] : g_xr0[j*128+t];
    for (int e = t; e < nE; e += 256) ssrc[e] = g_in_src[base+e];
    __syncthreads();
    for (int idx = t; idx < nE*2; idx += 256) {
      const int e = idx >> 1, h = idx & 1, s = ssrc[e];
      const float* xls = ((s == i) ? g_xlV : g_xl0) + s*128 + h*64;
      float acc = 0.f;
      #pragma unroll
      for (int c = 0; c < 64; ++c) {
        float v = xls[c] + sxr[h*64+c];
        v = v > 0.f ? v : 0.2f*v;
        acc += satt[h*64+c]*v;
      }
      slog[h][e] = acc;
    }
    __syncthreads();
    if (t < 128) {
      const int h = t >> 6, lane = t & 63;
      float m = -1e30f;
      for (int e = lane; e < nE; e += 64) m = fmaxf(m, slog[h][e]);
      for (int o = 1; o < 64; o <<= 1) m = fmaxf(m, __shfl_xor(m, o));
      float ssum = 0.f;
      for (int e = lane; e < nE; e += 64) { const float w = __expf(slog[h][e]-m); sw[h][e] = w; ssum += w; }
      for (int o = 1; o < 64; o <<= 1) ssum += __shfl_xor(ssum, o);
      if (lane == 0) sinv[h] = 1.f/(ssum + 1e-16f);
    }
    __syncthreads();
    if (t < 128) {
      const int h = t >> 6, c = t & 63;
      float acc = 0.f;
      for (int e = 0; e < nE; ++e) {
        const int s = ssrc[e];
        const float* xls = ((s == i) ? g_xlV : g_xl0) + s*128;
        acc += sw[h][e]*xls[h*64+c];
      }
      sagg[t] = acc*sinv[h];
    }
    __syncthreads();
    if (t < 64) {
      float g = 0.5f*(sagg[t]+sagg[64+t]) + g_w[OFF_G1BIAS + t];
      g = g > 0.f ? g : expm1f(g);
      g1n[a*64+t] = g;
    }
    __syncthreads();
  }

  // ---- layer 2 at node i ----
  // per-edge xl2: changed sources recomputed, others from precompute
  for (int idx = t; idx < nE2*128; idx += 256) {
    const int e = idx >> 7, c = idx & 127, s = ssrc2[e];
    const int sl = slotOf[s];
    float v;
    if (sl >= 0) {
      v = g_w[OFF_G2BL + c];
      const float* g1r = g1n + sl*64;
      #pragma unroll
      for (int k = 0; k < 64; ++k) v += g1r[k]*g_w[OFF_G2WL + k*128+c];
    } else {
      v = g_xl2_0[s*128+c];
    }
    xl2e[e*128+c] = v;
  }
  if (t < 128) {
    float v = g_w[OFF_G2BR + t];
    const float* g1r = g1n;          // slot 0 == node i
    #pragma unroll
    for (int k = 0; k < 64; ++k) v += g1r[k]*g_w[OFF_G2WR + k*128+t];
    xr2i[t] = v;
  }
  __syncthreads();
  for (int idx = t; idx < nE2*2; idx += 256) {
    const int e = idx >> 1, h = idx & 1;
    const float* xle = xl2e + e*128 + h*64;
    float acc = 0.f;
    #pragma unroll
    for (int c = 0; c < 64; ++c) {
      float v = xle[c] + xr2i[h*64+c];
      v = v > 0.f ? v : 0.2f*v;
      acc += satt2[h*64+c]*v;
    }
    slog[h][e] = acc;
  }
  __syncthreads();
  if (t < 128) {
    const int h = t >> 6, lane = t & 63;
    float m = -1e30f;
    for (int e = lane; e < nE2; e += 64) m = fmaxf(m, slog[h][e]);
    for (int o = 1; o < 64; o <<= 1) m = fmaxf(m, __shfl_xor(m, o));
    float ssum = 0.f;
    for (int e = lane; e < nE2; e += 64) { const float w = __expf(slog[h][e]-m); sw[h][e] = w; ssum += w; }
    for (int o = 1; o < 64; o <<= 1) ssum += __shfl_xor(ssum, o);
    if (lane == 0) sinv[h] = 1.f/(ssum + 1e-16f);
  }
  __syncthreads();
  if (t < 128) {
    const int h = t >> 6, c = t & 63;
    float acc = 0.f;
    for (int e = 0; e < nE2; ++e) acc += sw[h][e]*xl2e[e*128 + h*64 + c];
    sagg[t] = acc*sinv[h];
  }
  __syncthreads();
  if (t < 64) {
    float g = 0.5f*(sagg[t]+sagg[64+t]) + g_w[OFF_G2BIAS + t];
    g = g > 0.f ? g : expm1f(g);
    sg[t] = g;
  }
  __syncthreads();
  if (t < 64) {
    float v = g_w[OFF_RECB + t];
    #pragma unroll
    for (int c = 0; c < 64; ++c) v += sg[c]*g_w[OFF_RECW + c*64+t];
    const float r = tanhf(v);
    if (g_f32) ((float*)out)[i*64+t] = r;
    else       ((__hip_bfloat16*)out)[i*64+t] = __float2bfloat16(r);
  }
}

// ---------------------------------------------------------------------------
extern "C" void kernel_launch(void* const* d_in, const int* in_sizes, int n_in,
                              void* d_out, int out_size, void* d_ws, size_t ws_size,
                              hipStream_t stream)
{
  const int* ei = (const int*)d_in[2];
  const int E = in_sizes[2] / 2;

  k_init<<<45, 256, 0, stream>>>(
      d_in[0], d_in[1], d_in[3], d_in[4], d_in[5], d_in[6], d_in[7],
      d_in[8], d_in[9], d_in[10], d_in[11], d_in[12], d_in[13], d_in[14],
      d_in[15], d_in[16], d_in[17], d_in[18], d_in[19], d_in[20], d_in[21],
      d_in[22], d_in[23], d_in[24], d_in[25],
      in_sizes[0], ei, E);
  k_dense<<<NN, 128, 0, stream>>>();
  k_l1base<<<NN, 128, 0, stream>>>();
  k_periter<<<NN, 256, 0, stream>>>(d_out);
}